// Round 9
// baseline (120.468 us; speedup 1.0000x reference)
//
#include <hip/hip_runtime.h>
#include <hip/hip_bf16.h>
#include <stdint.h>

#define B_ 2
#define S_ 2048
#define H_ 32
#define D_ 128
#define R_ (B_*H_*S_)           // 131072 rows per tensor (head-major)
#define PG 2048                 // prep grid size
#define QKU (2 * B_ * S_ * (H_/8))  // 32768 transpose units (q then k)
#define VSU (B_ * S_)           // 4096 vsum units
#define CPB 40                  // uniform k-chunks (<=8 64-row tiles) per bh

typedef __bf16 bf16x8 __attribute__((ext_vector_type(8)));
typedef float  f32x16 __attribute__((ext_vector_type(16)));

#if __has_builtin(__builtin_amdgcn_exp2f)
#define EXP2F(x) __builtin_amdgcn_exp2f(x)
#else
#define EXP2F(x) exp2f(x)
#endif

#define AS1 __attribute__((address_space(1)))
#define AS3 __attribute__((address_space(3)))

__device__ __forceinline__ unsigned short f2bf(float f) {
  unsigned u = __float_as_uint(f);
  u += 0x7FFFu + ((u >> 16) & 1u);
  return (unsigned short)(u >> 16);
}

// Grid-stride prep (2048 blocks -- the 37k-tiny-block version was capped by
// workgroup dispatch rate at ~480 wg/us, not bandwidth):
//   16 qk-units/block: q,k [B,S,H,D] fp32 -> [B,H,S,D] bf16 (Q gets
//     scale*log2e folded). Unit = 8 h-rows of one (b,s): 4KB contiguous read,
//     8 x 256B (full-line) scattered writes.
//   2 vsum-units/block: vsum[b,h,s] = sum_d v[b,s,h,d]; 16KB contiguous read.
//   First 256 blocks: zero num/den (float4 each).
__global__ __launch_bounds__(256) void prep(
    const float* __restrict__ q, const float* __restrict__ k,
    const float* __restrict__ v,
    unsigned short* __restrict__ qb, unsigned short* __restrict__ kb,
    float* __restrict__ vsum, float* __restrict__ nd, float* __restrict__ out0) {
  const int bid = blockIdx.x;
  const int t = threadIdx.x;
  if (bid == 0 && t == 0) out0[0] = 0.f;

  #pragma unroll 4
  for (int g = 0; g < QKU / PG; ++g) {
    const int u = bid + g * PG;
    const int which = u >= (QKU / 2);
    const int i2 = which ? u - (QKU / 2) : u;
    const float* src = which ? k : q;
    unsigned short* dst = which ? kb : qb;
    const float sc = which ? 1.0f : 0.0883883476483184f * 1.4426950408889634f;
    const int b   = i2 / (S_ * 4);
    const int rem = i2 % (S_ * 4);
    const int s   = rem >> 2;
    const int h   = (rem & 3) * 8 + (t >> 5);
    const int lane32 = t & 31;
    const float4 v4 = *reinterpret_cast<const float4*>(
        src + (((size_t)b * S_ + s) * H_ + h) * D_ + lane32 * 4);
    ushort4 o;
    o.x = f2bf(v4.x * sc); o.y = f2bf(v4.y * sc);
    o.z = f2bf(v4.z * sc); o.w = f2bf(v4.w * sc);
    *reinterpret_cast<ushort4*>(
        dst + (((size_t)b * H_ + h) * S_ + s) * D_ + lane32 * 4) = o;
  }

  #pragma unroll
  for (int g = 0; g < VSU / PG; ++g) {
    const int u = bid + g * PG;
    const int b = u / S_, s = u % S_;
    const int h = t >> 3, i = t & 7;   // 8 lanes per h-row
    const float* p = v + (((size_t)b * S_ + s) * H_ + h) * D_ + i * 16;
    const float4 a0 = *reinterpret_cast<const float4*>(p + 0);
    const float4 a1 = *reinterpret_cast<const float4*>(p + 4);
    const float4 a2 = *reinterpret_cast<const float4*>(p + 8);
    const float4 a3 = *reinterpret_cast<const float4*>(p + 12);
    float sum = (a0.x+a0.y+a0.z+a0.w) + (a1.x+a1.y+a1.z+a1.w)
              + (a2.x+a2.y+a2.z+a2.w) + (a3.x+a3.y+a3.z+a3.w);
    sum += __shfl_xor(sum, 1);
    sum += __shfl_xor(sum, 2);
    sum += __shfl_xor(sum, 4);
    if (i == 0) vsum[((size_t)b * H_ + h) * S_ + s] = sum;
  }

  if (bid < 256) {
    float4* p = reinterpret_cast<float4*>(nd);
    p[(size_t)bid * 256 + t] = float4{0.f, 0.f, 0.f, 0.f};
  }
}

// Main: block = (bh, qt 128 q-rows, uniform k-chunk). 32-row k-subtiles in a
// ring of 4 LDS slots (33KB -> 4 blocks/CU), DEPTH-2 prefetch with counted
// vmcnt + raw s_barrier (T3/T4): batch j drains to vmcnt(3) leaving batch j+1
// in flight across the barrier; batch j+2 issued right after. The loop issues
// ONLY global_load_lds VMEM (vsum strip rides the DMA batch wave-redundantly)
// so the per-wave count is exactly 3 ops/batch. Coalesced XOR-involution
// staging (1KB contiguous per DMA, bank-balanced ds_read_b128) from R8.
__global__ __launch_bounds__(256, 4) void attn_sum(
    const unsigned short* __restrict__ qg_, const unsigned short* __restrict__ kg_,
    const float* __restrict__ vsum, float* __restrict__ numb,
    float* __restrict__ denb) {
  __shared__ uint4 kbuf[4][512];       // 4 x 8KB
  __shared__ float vsbuf[4][64];       // 4 x 256B

  // id -> (bh, chunk c): same-bh blocks share id%8 -> likely same XCD.
  const int id = blockIdx.x;
  const int y  = id >> 3;
  const int bh = (id & 7) + 8 * (y / CPB);
  const int c  = y % CPB;

  // chunk table (64-row tiles): qt 0-3 -> 1 chunk; 4-7 -> 2; 8-11 -> 3;
  // 12-15 -> 4. Subtile range = 2x tile range.
  int qt, h, nch;
  if (c < 4)       { qt = c;                 h = 0;            nch = 1; }
  else if (c < 12) { qt = 4 + ((c - 4) >> 1);  h = (c - 4) & 1;  nch = 2; }
  else if (c < 24) { qt = 8 + (c - 12) / 3;    h = (c - 12) % 3; nch = 3; }
  else             { qt = 12 + ((c - 24) >> 2); h = (c - 24) & 3; nch = 4; }
  const int nkt  = 2 * qt + 2;
  const int bas_ = nkt / nch, rem = nkt % nch;
  const int kt0  = h * bas_ + (h < rem ? h : rem);
  const int kt1  = kt0 + bas_ + (h < rem ? 1 : 0);
  const int st0  = 2 * kt0, st1 = 2 * kt1;   // 32-row subtiles

  const int t  = threadIdx.x;
  const int w  = t >> 6;
  const int l  = t & 63;
  const int ln = l & 31, l5 = l >> 5;

  const size_t base = (size_t)bh * S_ * D_;
  const int qrow0 = qt * 128 + w * 32;
  const unsigned short* ksrc0 = kg_ + base;
  const float* vsrc0 = vsum + (size_t)bh * S_;

  // Q A-frags: 32 q-rows (m = lane&31), k-chunk d = kb8*16 + l5*8 .. +8.
  bf16x8 qfrag[8];
  {
    const unsigned short* qp = qg_ + base + (size_t)(qrow0 + ln) * D_ + l5 * 8;
    #pragma unroll
    for (int kb8 = 0; kb8 < 8; ++kb8)
      qfrag[kb8] = *reinterpret_cast<const bf16x8*>(qp + kb8 * 16);
  }

  // Stage one 32-row subtile: per wave 2 K-DMAs (1KB contiguous each) +
  // 1 vsum-DMA (wave-redundant, benign) = exactly 3 vmcnt ops.
  auto stage = [&](int st, int slot) {
    const unsigned short* ksrc = ksrc0 + (size_t)st * 32 * D_;
    #pragma unroll
    for (int j = 0; j < 2; ++j) {
      const int idx = (w * 2 + j) * 64 + l;   // physical 16B slot in subtile
      const int r   = idx >> 4;
      const int p   = idx & 15;
      const int cc  = p ^ (r & 15);           // logical chunk stored here
      const unsigned short* src = ksrc + r * D_ + cc * 8;
      __builtin_amdgcn_global_load_lds(
          (const AS1 void*)src, (AS3 void*)(&kbuf[slot][idx & ~63]), 16, 0, 0);
    }
    __builtin_amdgcn_global_load_lds(
        (const AS1 void*)(vsrc0 + st * 32 + l), (AS3 void*)(&vsbuf[slot][0]), 4, 0, 0);
  };

  float num[16], den[16];
  #pragma unroll
  for (int r = 0; r < 16; ++r) { num[r] = 0.f; den[r] = 0.f; }

  // Prologue: depth-2.
  stage(st0, st0 & 3);
  stage(st0 + 1, (st0 + 1) & 3);

  const int xr = ln & 15;
  for (int st = st0; st < st1; ++st) {
    // Drain batch st (3 ops), leave batch st+1 (3 ops) in flight.
    if (st + 1 < st1) asm volatile("s_waitcnt vmcnt(3)" ::: "memory");
    else              asm volatile("s_waitcnt vmcnt(0)" ::: "memory");
    __builtin_amdgcn_s_barrier();            // raw: no implicit drain
    if (st + 2 < st1) stage(st + 2, (st + 2) & 3);

    const int kbase = st * 32;
    if (kbase <= qrow0 + 31) {               // wave-uniform causal skip
      const int slot = st & 3;
      const uint4* rowb = &kbuf[slot][ln * 16];
      f32x16 sacc = {0.f,0.f,0.f,0.f,0.f,0.f,0.f,0.f,
                     0.f,0.f,0.f,0.f,0.f,0.f,0.f,0.f};
      __builtin_amdgcn_s_setprio(1);
      #pragma unroll
      for (int kb8 = 0; kb8 < 8; ++kb8) {
        const bf16x8 bf = *reinterpret_cast<const bf16x8*>(&rowb[(kb8 * 2 + l5) ^ xr]);
        sacc = __builtin_amdgcn_mfma_f32_32x32x16_bf16(qfrag[kb8], bf, sacc, 0, 0, 0);
      }
      __builtin_amdgcn_s_setprio(0);
      const float vsv = vsbuf[slot][ln];
      if (kbase + 31 <= qrow0) {
        #pragma unroll
        for (int r = 0; r < 16; ++r) {
          const float e = EXP2F(sacc[r]);
          den[r] += e;
          num[r] = fmaf(e, vsv, num[r]);
        }
      } else {
        const int kgc = kbase + ln;
        #pragma unroll
        for (int r = 0; r < 16; ++r) {
          const int qgr = qrow0 + (r & 3) + 8 * (r >> 2) + 4 * l5;
          const float e = (kgc <= qgr) ? EXP2F(sacc[r]) : 0.f;
          den[r] += e;
          num[r] = fmaf(e, vsv, num[r]);
        }
      }
    }
  }

  // Reduce over the 32 k-cols (lanes within each l5 half), then one atomic
  // pair per q-row from lane ln==0 of each half.
  #pragma unroll
  for (int m = 1; m < 32; m <<= 1) {
    #pragma unroll
    for (int r = 0; r < 16; ++r) {
      num[r] += __shfl_xor(num[r], m);
      den[r] += __shfl_xor(den[r], m);
    }
  }
  if (ln == 0) {
    float* nrow = numb + (size_t)bh * S_;
    float* drow = denb + (size_t)bh * S_;
    #pragma unroll
    for (int r = 0; r < 16; ++r) {
      const int qgr = qrow0 + (r & 3) + 8 * (r >> 2) + 4 * l5;
      atomicAdd(&nrow[qgr], num[r]);
      atomicAdd(&drow[qgr], den[r]);
    }
  }
}

// Finalize: sum(num/den) over all q-rows.
__global__ __launch_bounds__(256) void finalize(
    const float* __restrict__ numb, const float* __restrict__ denb,
    float* __restrict__ out) {
  const int i = blockIdx.x * 256 + threadIdx.x;
  float c = numb[i] / denb[i];
  #pragma unroll
  for (int m = 1; m < 64; m <<= 1) c += __shfl_xor(c, m);
  __shared__ float ps[4];
  if ((threadIdx.x & 63) == 0) ps[threadIdx.x >> 6] = c;
  __syncthreads();
  if (threadIdx.x == 0) atomicAdd(out, ps[0] + ps[1] + ps[2] + ps[3]);
}

extern "C" void kernel_launch(void* const* d_in, const int* in_sizes, int n_in,
                              void* d_out, int out_size, void* d_ws, size_t ws_size,
                              hipStream_t stream) {
  const float* q = (const float*)d_in[0];
  const float* k = (const float*)d_in[1];
  const float* v = (const float*)d_in[2];
  float* out = (float*)d_out;

  unsigned short* qb = (unsigned short*)d_ws;                 // 32 MiB
  unsigned short* kb = qb + (size_t)R_ * D_;                  // 32 MiB
  float* vsum = (float*)(kb + (size_t)R_ * D_);               // 512 KiB
  float* numb = vsum + R_;                                    // 512 KiB
  float* denb = numb + R_;                                    // 512 KiB

  hipLaunchKernelGGL(prep, dim3(PG), dim3(256), 0, stream,
                     q, k, v, qb, kb, vsum, numb, out);
  hipLaunchKernelGGL(attn_sum, dim3(64 * CPB), dim3(256), 0, stream,
                     qb, kb, vsum, numb, denb);
  hipLaunchKernelGGL(finalize, dim3(R_ / 256), dim3(256), 0, stream,
                     numb, denb, out);
}

// Round 10
// 111.500 us; speedup vs baseline: 1.0804x; 1.0804x over previous
//
#include <hip/hip_runtime.h>
#include <hip/hip_bf16.h>
#include <stdint.h>

#define B_ 2
#define S_ 2048
#define H_ 32
#define D_ 128
#define R_ (B_*H_*S_)           // 131072 (b,h,s) rows
#define PG 2048                 // prep grid size
#define VSU (B_ * S_)           // 4096 vsum units
#define CPB 40                  // uniform k-chunks (<=8 64-row tiles) per bh

typedef __bf16 bf16x8 __attribute__((ext_vector_type(8)));
typedef float  f32x16 __attribute__((ext_vector_type(16)));

#if __has_builtin(__builtin_amdgcn_exp2f)
#define EXP2F(x) __builtin_amdgcn_exp2f(x)
#else
#define EXP2F(x) exp2f(x)
#endif

#define AS1 __attribute__((address_space(1)))
#define AS3 __attribute__((address_space(3)))

__device__ __forceinline__ unsigned short f2bf(float f) {
  unsigned u = __float_as_uint(f);
  u += 0x7FFFu + ((u >> 16) & 1u);
  return (unsigned short)(u >> 16);
}

// Prep (pure streaming -- NO transpose; R6-R9's strided 256B-granule
// transpose was stuck at ~2.1 TB/s regardless of direction):
//   k [B,S,H,D] fp32 -> kb SAME layout bf16 (contiguous read AND write).
//   vsum[b,h,s] = sum_d v[b,s,h,d] (16KB contiguous panel reads).
//   First 256 blocks also zero num/den; block 0 zeros the output scalar.
__global__ __launch_bounds__(256) void prep(
    const float* __restrict__ k, const float* __restrict__ v,
    unsigned short* __restrict__ kb,
    float* __restrict__ vsum, float* __restrict__ nd, float* __restrict__ out0) {
  const int bid = blockIdx.x;
  const int t = threadIdx.x;
  if (bid == 0 && t == 0) out0[0] = 0.f;

  // k convert: 2,097,152 ushort8-groups, 4 per thread.
  #pragma unroll
  for (int g = 0; g < (R_ * D_ / 8) / (PG * 256); ++g) {
    const size_t i = (size_t)g * (PG * 256) + bid * 256 + t;
    const float4 a = *reinterpret_cast<const float4*>(k + i * 8);
    const float4 b = *reinterpret_cast<const float4*>(k + i * 8 + 4);
    ushort4 o0, o1;
    o0.x = f2bf(a.x); o0.y = f2bf(a.y); o0.z = f2bf(a.z); o0.w = f2bf(a.w);
    o1.x = f2bf(b.x); o1.y = f2bf(b.y); o1.z = f2bf(b.z); o1.w = f2bf(b.w);
    *reinterpret_cast<ushort4*>(kb + i * 8)     = o0;
    *reinterpret_cast<ushort4*>(kb + i * 8 + 4) = o1;
  }

  // vsum: block reads one (b,s) panel (16KB contiguous), 8 lanes per h-row.
  #pragma unroll
  for (int g = 0; g < VSU / PG; ++g) {
    const int u = bid + g * PG;
    const int b = u / S_, s = u % S_;
    const int h = t >> 3, i = t & 7;
    const float* p = v + (((size_t)b * S_ + s) * H_ + h) * D_ + i * 16;
    const float4 a0 = *reinterpret_cast<const float4*>(p + 0);
    const float4 a1 = *reinterpret_cast<const float4*>(p + 4);
    const float4 a2 = *reinterpret_cast<const float4*>(p + 8);
    const float4 a3 = *reinterpret_cast<const float4*>(p + 12);
    float sum = (a0.x+a0.y+a0.z+a0.w) + (a1.x+a1.y+a1.z+a1.w)
              + (a2.x+a2.y+a2.z+a2.w) + (a3.x+a3.y+a3.z+a3.w);
    sum += __shfl_xor(sum, 1);
    sum += __shfl_xor(sum, 2);
    sum += __shfl_xor(sum, 4);
    if (i == 0) vsum[((size_t)b * H_ + h) * S_ + s] = sum;
  }

  if (bid < 256) {
    float4* p = reinterpret_cast<float4*>(nd);
    p[(size_t)bid * 256 + t] = float4{0.f, 0.f, 0.f, 0.f};
  }
}

// Main: block = (bh, qt 128 q-rows, uniform k-chunk). R9's proven pipeline:
// 32-row k-subtiles, ring-4 LDS slots, depth-2 prefetch, counted vmcnt(3) +
// raw s_barrier (batches stay in flight across barriers). Changes vs R9:
//  - Q loaded directly from fp32 [B,S,H,D] (converted+scaled in registers,
//    once per block) -- qb buffer and its prep traffic deleted.
//  - K staged from bf16 [B,S,H,D]: row stride 8KB, each DMA = 4 x 256B
//    segments = 16 full lines (no inflation); kb is 32MiB -> L3-resident.
//  - XOR-involution LDS swizzle unchanged (bank-balanced ds_read_b128).
__global__ __launch_bounds__(256, 4) void attn_sum(
    const float* __restrict__ qf_, const unsigned short* __restrict__ kb_,
    const float* __restrict__ vsum, float* __restrict__ numb,
    float* __restrict__ denb) {
  __shared__ uint4 kbuf[4][512];       // 4 x 8KB
  __shared__ float vsbuf[4][64];       // 4 x 256B

  // id -> (bh, chunk c): same-bh blocks share id%8 -> likely same XCD.
  const int id = blockIdx.x;
  const int y  = id >> 3;
  const int bh = (id & 7) + 8 * (y / CPB);
  const int c  = y % CPB;

  // chunk table (64-row tiles): qt 0-3 -> 1 chunk; 4-7 -> 2; 8-11 -> 3;
  // 12-15 -> 4.
  int qt, h, nch;
  if (c < 4)       { qt = c;                 h = 0;            nch = 1; }
  else if (c < 12) { qt = 4 + ((c - 4) >> 1);  h = (c - 4) & 1;  nch = 2; }
  else if (c < 24) { qt = 8 + (c - 12) / 3;    h = (c - 12) % 3; nch = 3; }
  else             { qt = 12 + ((c - 24) >> 2); h = (c - 24) & 3; nch = 4; }
  const int nkt  = 2 * qt + 2;
  const int bas_ = nkt / nch, rem = nkt % nch;
  const int kt0  = h * bas_ + (h < rem ? h : rem);
  const int kt1  = kt0 + bas_ + (h < rem ? 1 : 0);
  const int st0  = 2 * kt0, st1 = 2 * kt1;   // 32-row subtiles

  const int t  = threadIdx.x;
  const int w  = t >> 6;
  const int l  = t & 63;
  const int ln = l & 31, l5 = l >> 5;

  const int b0 = bh >> 5, h0 = bh & 31;
  const int qrow0 = qt * 128 + w * 32;
  const unsigned short* ksrc0 = kb_ + ((size_t)b0 * S_ * H_ + h0) * D_;
  const float* vsrc0 = vsum + (size_t)bh * S_;

  // Q A-frags direct from fp32 [B,S,H,D], scale*log2e folded in.
  const float sc = 0.0883883476483184f * 1.4426950408889634f;
  bf16x8 qfrag[8];
  {
    const float* qp = qf_ + (((size_t)b0 * S_ + qrow0 + ln) * H_ + h0) * D_ + l5 * 8;
    #pragma unroll
    for (int kb8 = 0; kb8 < 8; ++kb8) {
      const float4 a = *reinterpret_cast<const float4*>(qp + kb8 * 16);
      const float4 b = *reinterpret_cast<const float4*>(qp + kb8 * 16 + 4);
      union { unsigned short u[8]; bf16x8 v; } uu;
      uu.u[0] = f2bf(a.x * sc); uu.u[1] = f2bf(a.y * sc);
      uu.u[2] = f2bf(a.z * sc); uu.u[3] = f2bf(a.w * sc);
      uu.u[4] = f2bf(b.x * sc); uu.u[5] = f2bf(b.y * sc);
      uu.u[6] = f2bf(b.z * sc); uu.u[7] = f2bf(b.w * sc);
      qfrag[kb8] = uu.v;
    }
  }

  // Stage one 32-row subtile: 2 K-DMAs + 1 vsum-DMA = exactly 3 vmcnt ops.
  auto stage = [&](int st, int slot) {
    #pragma unroll
    for (int j = 0; j < 2; ++j) {
      const int idx = (w * 2 + j) * 64 + l;   // physical 16B slot in subtile
      const int r   = idx >> 4;
      const int p   = idx & 15;
      const int cc  = p ^ (r & 15);           // logical chunk stored here
      const unsigned short* src = ksrc0 + (size_t)(st * 32 + r) * (H_ * D_) + cc * 8;
      __builtin_amdgcn_global_load_lds(
          (const AS1 void*)src, (AS3 void*)(&kbuf[slot][idx & ~63]), 16, 0, 0);
    }
    __builtin_amdgcn_global_load_lds(
        (const AS1 void*)(vsrc0 + st * 32 + l), (AS3 void*)(&vsbuf[slot][0]), 4, 0, 0);
  };

  float num[16], den[16];
  #pragma unroll
  for (int r = 0; r < 16; ++r) { num[r] = 0.f; den[r] = 0.f; }

  // Prologue: depth-2.
  stage(st0, st0 & 3);
  stage(st0 + 1, (st0 + 1) & 3);

  const int xr = ln & 15;
  for (int st = st0; st < st1; ++st) {
    // Drain batch st (3 ops), leave batch st+1 (3 ops) in flight.
    if (st + 1 < st1) asm volatile("s_waitcnt vmcnt(3)" ::: "memory");
    else              asm volatile("s_waitcnt vmcnt(0)" ::: "memory");
    __builtin_amdgcn_s_barrier();            // raw: no implicit drain
    if (st + 2 < st1) stage(st + 2, (st + 2) & 3);

    const int kbase = st * 32;
    if (kbase <= qrow0 + 31) {               // wave-uniform causal skip
      const int slot = st & 3;
      const uint4* rowb = &kbuf[slot][ln * 16];
      f32x16 sacc = {0.f,0.f,0.f,0.f,0.f,0.f,0.f,0.f,
                     0.f,0.f,0.f,0.f,0.f,0.f,0.f,0.f};
      __builtin_amdgcn_s_setprio(1);
      #pragma unroll
      for (int kb8 = 0; kb8 < 8; ++kb8) {
        const bf16x8 bf = *reinterpret_cast<const bf16x8*>(&rowb[(kb8 * 2 + l5) ^ xr]);
        sacc = __builtin_amdgcn_mfma_f32_32x32x16_bf16(qfrag[kb8], bf, sacc, 0, 0, 0);
      }
      __builtin_amdgcn_s_setprio(0);
      const float vsv = vsbuf[slot][ln];
      if (kbase + 31 <= qrow0) {
        #pragma unroll
        for (int r = 0; r < 16; ++r) {
          const float e = EXP2F(sacc[r]);
          den[r] += e;
          num[r] = fmaf(e, vsv, num[r]);
        }
      } else {
        const int kgc = kbase + ln;
        #pragma unroll
        for (int r = 0; r < 16; ++r) {
          const int qgr = qrow0 + (r & 3) + 8 * (r >> 2) + 4 * l5;
          const float e = (kgc <= qgr) ? EXP2F(sacc[r]) : 0.f;
          den[r] += e;
          num[r] = fmaf(e, vsv, num[r]);
        }
      }
    }
  }

  // Reduce over the 32 k-cols, then one atomic pair per q-row.
  #pragma unroll
  for (int m = 1; m < 32; m <<= 1) {
    #pragma unroll
    for (int r = 0; r < 16; ++r) {
      num[r] += __shfl_xor(num[r], m);
      den[r] += __shfl_xor(den[r], m);
    }
  }
  if (ln == 0) {
    float* nrow = numb + (size_t)bh * S_;
    float* drow = denb + (size_t)bh * S_;
    #pragma unroll
    for (int r = 0; r < 16; ++r) {
      const int qgr = qrow0 + (r & 3) + 8 * (r >> 2) + 4 * l5;
      atomicAdd(&nrow[qgr], num[r]);
      atomicAdd(&drow[qgr], den[r]);
    }
  }
}

// Finalize: sum(num/den) over all q-rows.
__global__ __launch_bounds__(256) void finalize(
    const float* __restrict__ numb, const float* __restrict__ denb,
    float* __restrict__ out) {
  const int i = blockIdx.x * 256 + threadIdx.x;
  float c = numb[i] / denb[i];
  #pragma unroll
  for (int m = 1; m < 64; m <<= 1) c += __shfl_xor(c, m);
  __shared__ float ps[4];
  if ((threadIdx.x & 63) == 0) ps[threadIdx.x >> 6] = c;
  __syncthreads();
  if (threadIdx.x == 0) atomicAdd(out, ps[0] + ps[1] + ps[2] + ps[3]);
}

extern "C" void kernel_launch(void* const* d_in, const int* in_sizes, int n_in,
                              void* d_out, int out_size, void* d_ws, size_t ws_size,
                              hipStream_t stream) {
  const float* q = (const float*)d_in[0];
  const float* k = (const float*)d_in[1];
  const float* v = (const float*)d_in[2];
  float* out = (float*)d_out;

  unsigned short* kb = (unsigned short*)d_ws;                 // 32 MiB
  float* vsum = (float*)(kb + (size_t)R_ * D_);               // 512 KiB
  float* numb = vsum + R_;                                    // 512 KiB
  float* denb = numb + R_;                                    // 512 KiB

  hipLaunchKernelGGL(prep, dim3(PG), dim3(256), 0, stream,
                     k, v, kb, vsum, numb, out);
  hipLaunchKernelGGL(attn_sum, dim3(64 * CPB), dim3(256), 0, stream,
                     q, kb, vsum, numb, denb);
  hipLaunchKernelGGL(finalize, dim3(R_ / 256), dim3(256), 0, stream,
                     numb, denb, out);
}